// Round 11
// baseline (98.235 us; speedup 1.0000x reference)
//
#include <hip/hip_runtime.h>
#include <math.h>

typedef short bf16x8 __attribute__((ext_vector_type(8)));
typedef float f32x4  __attribute__((ext_vector_type(4)));

constexpr int   B_    = 4;
constexpr int   N_    = 2048;
constexpr int   INF_  = 256;
constexpr int   OUTF_ = 128;
constexpr float LAMBDA_INIT_ = 0.35550906759096926f;
constexpr float OUT_SCALE_   = 0.64449093240903074f;   // 1 - LAMBDA_INIT
constexpr float EPS_         = 1e-5f;
constexpr float LOG2E_       = 1.44269504088896340736f;

__device__ inline unsigned short f2bf(float x) {
  unsigned u = __float_as_uint(x);
  u += 0x7fffu + ((u >> 16) & 1u);          // round-to-nearest-even
  return (unsigned short)(u >> 16);
}
__device__ inline unsigned pack2(float a, float b) {
  return (unsigned)f2bf(a) | ((unsigned)f2bf(b) << 16);
}

// ---------------- Kernel A: tiny scalars (rel scores + lambda), log2e-scaled ----------------
__global__ void scalars_kernel(const float* __restrict__ rel_emb,
                               const float* __restrict__ a_rel_pos,
                               const float* __restrict__ a_rel_neg,
                               const float* __restrict__ ll1, const float* __restrict__ lr1,
                               const float* __restrict__ ll2, const float* __restrict__ lr2,
                               float* __restrict__ scal) {
  int lane = threadIdx.x;  // 64 threads, 1 wave
  float p1 = ll1[lane] * lr1[lane];
  float p2 = ll2[lane] * lr2[lane];
  #pragma unroll
  for (int off = 32; off; off >>= 1) { p1 += __shfl_xor(p1, off); p2 += __shfl_xor(p2, off); }
  if (lane == 0) scal[12] = expf(p1) - expf(p2) + LAMBDA_INIT_;   // lam: NOT scaled
  if (lane < 6) {
    float sp = 0.f, sn = 0.f;
    for (int k = 0; k < 10; ++k) {
      float rv = rel_emb[lane * 10 + k];
      sp += rv * a_rel_pos[k];
      sn += rv * a_rel_neg[k];
    }
    scal[lane]     = sp * LOG2E_;
    scal[6 + lane] = sn * LOG2E_;
  }
}

// ---------------- Kernel B: Wh = h @ W (fp32) + transposed bf16 copy ----------------
__global__ __launch_bounds__(256) void wh_kernel(const float* __restrict__ h,
                                                 const float* __restrict__ W,
                                                 float* __restrict__ Wh,
                                                 unsigned short* __restrict__ WhvT) {
  __shared__ __align__(16) float hT[INF_][20];
  const int t = threadIdx.x;
  const size_t row0 = (size_t)blockIdx.x * 16;
  #pragma unroll
  for (int i = 0; i < 16; ++i) hT[t][i] = h[(row0 + i) * INF_ + t];
  __syncthreads();
  const int c  = t & 127;
  const int rg = t >> 7;
  float acc[8] = {0.f, 0.f, 0.f, 0.f, 0.f, 0.f, 0.f, 0.f};
  #pragma unroll 4
  for (int k = 0; k < INF_; ++k) {
    float wv = W[k * OUTF_ + c];
    const float4* hp = reinterpret_cast<const float4*>(&hT[k][rg * 8]);
    float4 h0 = hp[0], h1 = hp[1];
    acc[0] += h0.x * wv; acc[1] += h0.y * wv; acc[2] += h0.z * wv; acc[3] += h0.w * wv;
    acc[4] += h1.x * wv; acc[5] += h1.y * wv; acc[6] += h1.z * wv; acc[7] += h1.w * wv;
  }
  #pragma unroll
  for (int r = 0; r < 8; ++r) Wh[(row0 + rg * 8 + r) * OUTF_ + c] = acc[r];
  uint4 pk;
  pk.x = pack2(acc[0], acc[1]); pk.y = pack2(acc[2], acc[3]);
  pk.z = pack2(acc[4], acc[5]); pk.w = pack2(acc[6], acc[7]);
  const int b  = (int)(row0 >> 11);
  const int n0 = (int)(row0 & 2047) + rg * 8;
  *reinterpret_cast<uint4*>(WhvT + ((size_t)b * OUTF_ + c) * N_ + n0) = pk;
}

// ---------------- Kernel C: per-node dot scores, pre-scaled by log2e ----------------
__global__ __launch_bounds__(256) void dots_kernel(const float* __restrict__ Wh,
                                                   const float* __restrict__ alp, const float* __restrict__ arp,
                                                   const float* __restrict__ aln, const float* __restrict__ arn,
                                                   float* __restrict__ lposv, float* __restrict__ rposv,
                                                   float* __restrict__ lnegv, float* __restrict__ rnegv) {
  const int t = threadIdx.x;
  const int wid = t >> 6, lane = t & 63;
  const int node = blockIdx.x * 4 + wid;
  float wp = Wh[(size_t)node * OUTF_ + lane];
  float wn = Wh[(size_t)node * OUTF_ + 64 + lane];
  float s0 = wp * alp[lane], s1 = wp * arp[lane];
  float s2 = wn * aln[lane], s3 = wn * arn[lane];
  #pragma unroll
  for (int off = 32; off; off >>= 1) {
    s0 += __shfl_xor(s0, off); s1 += __shfl_xor(s1, off);
    s2 += __shfl_xor(s2, off); s3 += __shfl_xor(s3, off);
  }
  if (lane == 0) {
    lposv[node] = s0 * LOG2E_; rposv[node] = s1 * LOG2E_;
    lnegv[node] = s2 * LOG2E_; rnegv[node] = s3 * LOG2E_;
  }
}

// ---------------- Kernel D1: attention rows, 4 j's/thread; light sum tail ----------------
// 8192 blocks x 512 threads = one row per block; thread t covers j = t*4..t*4+3.
// Same math as r10's passing attn_v3b; only the post-barrier total-sum read is
// restructured: 2 LDS reads + 6 shfl instead of 16 LDS reads (DS-pipe relief).
__global__ __launch_bounds__(512) void attn_v3c(
    const int* __restrict__ adj,
    const float* __restrict__ lposv, const float* __restrict__ rposv,
    const float* __restrict__ lnegv, const float* __restrict__ rnegv,
    const float* __restrict__ scal, float* __restrict__ out1,
    unsigned short* __restrict__ abf, int writeAbf) {
  __shared__ float sums[16];   // [P:0..7 | N:8..15] per wave
  const int t = threadIdx.x;
  const int lane = t & 63;
  const int wv = t >> 6;
  const int flat = blockIdx.x;        // b*N + i
  const int b = flat >> 11;

  const float lam = scal[12];
  float srcP = -1.0e30f, srcN = -1.0e30f;
  if (lane >= 1 && lane <= 5) { srcP = scal[lane]; srcN = scal[6 + lane]; }
  const int iSrcP = __float_as_int(srcP);
  const int iSrcN = __float_as_int(srcN);

  const float lP = lposv[flat];
  const float lN = lnegv[flat];
  const int j0 = t * 4;
  int4   av4 = *reinterpret_cast<const int4*>(adj + (size_t)flat * N_ + j0);
  float4 rp4 = *reinterpret_cast<const float4*>(rposv + b * N_ + j0);
  float4 rn4 = *reinterpret_cast<const float4*>(rnegv + b * N_ + j0);
  int   av[4] = {av4.x, av4.y, av4.z, av4.w};
  float rp[4] = {rp4.x, rp4.y, rp4.z, rp4.w};
  float rn[4] = {rn4.x, rn4.y, rn4.z, rn4.w};

  float p[4], n[4];
  #pragma unroll
  for (int q = 0; q < 4; ++q) {
    float rsp = __int_as_float(__builtin_amdgcn_ds_bpermute(av[q] << 2, iSrcP));
    float rsn = __int_as_float(__builtin_amdgcn_ds_bpermute(av[q] << 2, iSrcN));
    float e  = lP + rp[q] + rsp;
    float en = lN + rn[q] + rsn;
    e  = fmaxf(e, 0.2f * e);                 // leaky (pos scale commutes with log2e)
    en = fmaxf(en, 0.2f * en);
    p[q] = __builtin_amdgcn_exp2f(e);
    n[q] = __builtin_amdgcn_exp2f(en);
  }
  float sP = (p[0] + p[1]) + (p[2] + p[3]);
  float sN = (n[0] + n[1]) + (n[2] + n[3]);
  #pragma unroll
  for (int off = 32; off; off >>= 1) { sP += __shfl_xor(sP, off); sN += __shfl_xor(sN, off); }
  if (lane == 0) { sums[wv] = sP; sums[8 + wv] = sN; }
  __syncthreads();
  // total sums: 2 broadcast-ish LDS reads + 3-level shfl each (all-positive fp32)
  float vP = sums[lane & 7];
  vP += __shfl_xor(vP, 1); vP += __shfl_xor(vP, 2); vP += __shfl_xor(vP, 4);
  float vN = sums[8 + (lane & 7)];
  vN += __shfl_xor(vN, 1); vN += __shfl_xor(vN, 2); vN += __shfl_xor(vN, 4);
  const float s1 = 1.f / vP;
  const float s2 = -lam / vN;

  float a[4];
  #pragma unroll
  for (int q = 0; q < 4; ++q) a[q] = p[q] * s1 + n[q] * s2;
  float* o1 = out1 + (size_t)flat * N_ + j0;
  *reinterpret_cast<float4*>(o1) = make_float4(a[0], a[1], a[2], a[3]);
  if (writeAbf) {
    uint2 u;
    u.x = pack2(a[0], a[1]); u.y = pack2(a[2], a[3]);
    *reinterpret_cast<uint2*>(abf + (size_t)flat * N_ + j0) = u;
  }
}

// ---------------- Kernel D2: PV via MFMA, 16 waves, chunk-pair parallel ----------------
// 512 blocks x 1024 threads. Block: 16 rows x 128 ch, K = 2048 in 8 chunks of 256,
// processed as 4 pairs: waves 0-7 compute even chunk, waves 8-15 odd chunk.
// Pair-level LDS double buffer (A4[2 pair-bufs][2 chunks][512 units]) + reg prefetch.
// MFMA fragment/swizzle indexing identical to r10's passing pv_v5.
__global__ __launch_bounds__(1024, 8) void pv_v6(
    const float* __restrict__ attn, const unsigned short* __restrict__ abf, int useAbf,
    const unsigned short* __restrict__ WhvT,
    const float* __restrict__ gamma, const float* __restrict__ beta,
    float* __restrict__ out0) {
  __shared__ __align__(16) uint4 A4[2][2][512];     // 32 KB
  __shared__ __align__(16) float hp2[2][16][132];   // 16.9 KB
  const int t = threadIdx.x;
  const int lane = t & 63;
  const int w = t >> 6;              // 0..15
  const int bi = blockIdx.x;
  const int b  = bi >> 7;
  const int i0 = (bi & 127) * 16;

  // ---- staging coords: thread covers row sr, unit sj of a chunk-pair (64 units/row/pair)
  const int sr = t >> 6;             // 0..15
  const int sj = t & 63;             // 0..63: [0,32) -> chunk buf 0, [32,64) -> buf 1
  const int sbuf = sj >> 5;
  const int su   = sj & 31;
  const int swz  = sr & 7;
  const int slot = sr * 32 + (su ^ swz);
  const uint4* srcU = reinterpret_cast<const uint4*>(
      abf + ((size_t)(b * N_ + i0 + sr)) * N_) + sj;          // pair stride = 64 units
  const float4* src4 = reinterpret_cast<const float4*>(
      attn + ((size_t)(b * N_ + i0 + sr)) * N_) + sj * 2;     // pair stride = 128 float4

  // ---- compute coords: wave w -> chunk-of-pair cw = w>>3, ch tile (w&7)*16
  const int cw  = w >> 3;
  const int bl  = lane & 15;
  const int kg  = lane >> 4;
  const int ch  = (w & 7) * 16 + bl;
  const unsigned short* Bp = WhvT + ((size_t)b * OUTF_ + ch) * N_ + kg * 8;
  f32x4 acc = {0.f, 0.f, 0.f, 0.f};
  const int arow = bl * 32;
  const int aswz = bl & 7;

  // ---- stage pair 0 into pair-buf 0
  if (useAbf) {
    A4[0][sbuf][slot] = srcU[0];
  } else {
    float4 s0 = src4[0], s1 = src4[1];
    uint4 u;
    u.x = pack2(s0.x, s0.y); u.y = pack2(s0.z, s0.w);
    u.z = pack2(s1.x, s1.y); u.w = pack2(s1.z, s1.w);
    A4[0][sbuf][slot] = u;
  }
  __syncthreads();

  for (int pi = 0; pi < 4; ++pi) {
    const int pb = pi & 1;
    float4 s0, s1;
    uint4 t0;
    if (pi < 3) {  // issue next pair's global loads before the MFMA cluster
      if (useAbf) t0 = srcU[(pi + 1) * 64];
      else { s0 = src4[(pi + 1) * 128]; s1 = src4[(pi + 1) * 128 + 1]; }
    }
    // compute chunk c = 2*pi + cw from pair-buf pb
    const int c = 2 * pi + cw;
    const unsigned short* bp = Bp + c * 256;
    #pragma unroll
    for (int kk = 0; kk < 8; ++kk) {
      bf16x8 a  = *reinterpret_cast<const bf16x8*>(&A4[pb][cw][arow + ((kk * 4 + kg) ^ aswz)]);
      bf16x8 bv = *reinterpret_cast<const bf16x8*>(bp + kk * 32);
      acc = __builtin_amdgcn_mfma_f32_16x16x32_bf16(a, bv, acc, 0, 0, 0);
    }
    if (pi < 3) {  // write next pair into the other pair-buf
      if (useAbf) {
        A4[pb ^ 1][sbuf][slot] = t0;
      } else {
        uint4 u;
        u.x = pack2(s0.x, s0.y); u.y = pack2(s0.z, s0.w);
        u.z = pack2(s1.x, s1.y); u.w = pack2(s1.z, s1.w);
        A4[pb ^ 1][sbuf][slot] = u;
      }
    }
    __syncthreads();
  }

  // ---- partial-C dump: two waves per ch tile write distinct cw slots
  #pragma unroll
  for (int q = 0; q < 4; ++q) hp2[cw][kg * 4 + q][ch] = acc[q];
  __syncthreads();

  // ---- epilogue (r4's verified 512-thread LN+GELU; threads >=512 idle)
  if (t < 512) {
    const int row = t >> 5;
    const int c0  = t & 31;
    float v[4], s = 0.f, sq = 0.f;
    #pragma unroll
    for (int e = 0; e < 4; ++e) {
      const int chh = c0 + e * 32;
      v[e] = hp2[0][row][chh] + hp2[1][row][chh];
      s += v[e]; sq += v[e] * v[e];
    }
    #pragma unroll
    for (int off = 16; off; off >>= 1) { s += __shfl_xor(s, off); sq += __shfl_xor(sq, off); }
    const float mu  = s  * (1.f / 128.f);
    const float var = sq * (1.f / 128.f) - mu * mu;
    const float inv = rsqrtf(var + EPS_);
    float* orow = out0 + ((size_t)(b * N_ + i0 + row)) * OUTF_;
    #pragma unroll
    for (int e = 0; e < 4; ++e) {
      const int chh = c0 + e * 32;
      float y = (v[e] - mu) * inv * gamma[chh] + beta[chh];
      y *= OUT_SCALE_;
      orow[chh] = 0.5f * y * (1.f + erff(y * 0.70710678118654752f));
    }
  }
}

extern "C" void kernel_launch(void* const* d_in, const int* in_sizes, int n_in,
                              void* d_out, int out_size, void* d_ws, size_t ws_size,
                              hipStream_t stream) {
  (void)in_sizes; (void)n_in; (void)out_size;
  const float* h        = (const float*)d_in[0];
  const int*   adj      = (const int*)d_in[1];
  const float* W        = (const float*)d_in[2];
  const float* alp      = (const float*)d_in[3];
  const float* arp      = (const float*)d_in[4];
  const float* aln      = (const float*)d_in[5];
  const float* arn      = (const float*)d_in[6];
  const float* rel_emb  = (const float*)d_in[7];
  const float* a_rel_p  = (const float*)d_in[8];
  const float* a_rel_n  = (const float*)d_in[9];
  const float* ll1      = (const float*)d_in[10];
  const float* lr1      = (const float*)d_in[11];
  const float* ll2      = (const float*)d_in[12];
  const float* lr2      = (const float*)d_in[13];
  const float* gamma    = (const float*)d_in[14];
  const float* beta     = (const float*)d_in[15];

  float* out0 = (float*)d_out;                          // gelu(h'): B*N*OUTF
  float* out1 = out0 + (size_t)B_ * N_ * OUTF_;         // attention: B*N*N

  float* ws    = (float*)d_ws;
  float* scal  = ws;                    // 32 floats
  float* lposv = ws + 32;               // B*N
  float* rposv = lposv + B_ * N_;
  float* lnegv = rposv + B_ * N_;
  float* rnegv = lnegv + B_ * N_;
  float* Wh    = rnegv + B_ * N_;       // B*N*OUTF fp32
  unsigned short* WhvT = (unsigned short*)(Wh + (size_t)B_ * N_ * OUTF_);  // [B][OUTF][N] bf16
  unsigned short* Abf  = WhvT + (size_t)B_ * N_ * OUTF_;                   // [B*N][N] bf16

  // ws budget gate for the bf16 attention panel
  const size_t need = (size_t)(32 + 4 * B_ * N_ + B_ * N_ * OUTF_) * 4
                    + (size_t)B_ * N_ * OUTF_ * 2
                    + (size_t)B_ * N_ * N_ * 2;
  const int useAbf = (ws_size >= need) ? 1 : 0;

  scalars_kernel<<<1, 64, 0, stream>>>(rel_emb, a_rel_p, a_rel_n, ll1, lr1, ll2, lr2, scal);
  wh_kernel<<<(B_ * N_) / 16, 256, 0, stream>>>(h, W, Wh, WhvT);
  dots_kernel<<<(B_ * N_) / 4, 256, 0, stream>>>(Wh, alp, arp, aln, arn, lposv, rposv, lnegv, rnegv);
  attn_v3c<<<B_ * N_, 512, 0, stream>>>(adj, lposv, rposv, lnegv, rnegv, scal, out1, Abf, useAbf);
  pv_v6<<<B_ * (N_ / 16), 1024, 0, stream>>>(out1, Abf, useAbf, WhvT, gamma, beta, out0);
}

// Round 12
// 91.301 us; speedup vs baseline: 1.0759x; 1.0759x over previous
//
#include <hip/hip_runtime.h>
#include <math.h>

typedef short bf16x8 __attribute__((ext_vector_type(8)));
typedef float f32x4  __attribute__((ext_vector_type(4)));

constexpr int   B_    = 4;
constexpr int   N_    = 2048;
constexpr int   INF_  = 256;
constexpr int   OUTF_ = 128;
constexpr float LAMBDA_INIT_ = 0.35550906759096926f;
constexpr float OUT_SCALE_   = 0.64449093240903074f;   // 1 - LAMBDA_INIT
constexpr float EPS_         = 1e-5f;
constexpr float LOG2E_       = 1.44269504088896340736f;

__device__ inline unsigned short f2bf(float x) {
  unsigned u = __float_as_uint(x);
  u += 0x7fffu + ((u >> 16) & 1u);          // round-to-nearest-even
  return (unsigned short)(u >> 16);
}
__device__ inline unsigned pack2(float a, float b) {
  return (unsigned)f2bf(a) | ((unsigned)f2bf(b) << 16);
}

// ---------------- Kernel A: tiny scalars (rel scores + lambda), log2e-scaled ----------------
__global__ void scalars_kernel(const float* __restrict__ rel_emb,
                               const float* __restrict__ a_rel_pos,
                               const float* __restrict__ a_rel_neg,
                               const float* __restrict__ ll1, const float* __restrict__ lr1,
                               const float* __restrict__ ll2, const float* __restrict__ lr2,
                               float* __restrict__ scal) {
  int lane = threadIdx.x;  // 64 threads, 1 wave
  float p1 = ll1[lane] * lr1[lane];
  float p2 = ll2[lane] * lr2[lane];
  #pragma unroll
  for (int off = 32; off; off >>= 1) { p1 += __shfl_xor(p1, off); p2 += __shfl_xor(p2, off); }
  if (lane == 0) scal[12] = expf(p1) - expf(p2) + LAMBDA_INIT_;   // lam: NOT scaled
  if (lane < 6) {
    float sp = 0.f, sn = 0.f;
    for (int k = 0; k < 10; ++k) {
      float rv = rel_emb[lane * 10 + k];
      sp += rv * a_rel_pos[k];
      sn += rv * a_rel_neg[k];
    }
    scal[lane]     = sp * LOG2E_;
    scal[6 + lane] = sn * LOG2E_;
  }
}

// ---------------- Kernel B: Wh = h @ W (fp32) + transposed bf16 copy + fused dots ----------------
// 512 blocks x 256 threads; 16 rows x 128 ch. After the GEMM, each wave (64 lanes = one
// 64-ch half for one 8-row group) butterfly-reduces the 4 per-node dot products
// (identical reduce order to the verified dots_kernel -> bit-identical outputs).
__global__ __launch_bounds__(256) void wh_dots_kernel(
    const float* __restrict__ h, const float* __restrict__ W,
    const float* __restrict__ alp, const float* __restrict__ arp,
    const float* __restrict__ aln, const float* __restrict__ arn,
    float* __restrict__ Wh, unsigned short* __restrict__ WhvT,
    float* __restrict__ lposv, float* __restrict__ rposv,
    float* __restrict__ lnegv, float* __restrict__ rnegv) {
  __shared__ __align__(16) float hT[INF_][20];
  const int t = threadIdx.x;
  const size_t row0 = (size_t)blockIdx.x * 16;
  #pragma unroll
  for (int i = 0; i < 16; ++i) hT[t][i] = h[(row0 + i) * INF_ + t];
  __syncthreads();
  const int c  = t & 127;
  const int rg = t >> 7;
  float acc[8] = {0.f, 0.f, 0.f, 0.f, 0.f, 0.f, 0.f, 0.f};
  #pragma unroll 4
  for (int k = 0; k < INF_; ++k) {
    float wv = W[k * OUTF_ + c];
    const float4* hp = reinterpret_cast<const float4*>(&hT[k][rg * 8]);
    float4 h0 = hp[0], h1 = hp[1];
    acc[0] += h0.x * wv; acc[1] += h0.y * wv; acc[2] += h0.z * wv; acc[3] += h0.w * wv;
    acc[4] += h1.x * wv; acc[5] += h1.y * wv; acc[6] += h1.z * wv; acc[7] += h1.w * wv;
  }
  #pragma unroll
  for (int r = 0; r < 8; ++r) Wh[(row0 + rg * 8 + r) * OUTF_ + c] = acc[r];
  uint4 pk;
  pk.x = pack2(acc[0], acc[1]); pk.y = pack2(acc[2], acc[3]);
  pk.z = pack2(acc[4], acc[5]); pk.w = pack2(acc[6], acc[7]);
  const int b  = (int)(row0 >> 11);
  const int n0 = (int)(row0 & 2047) + rg * 8;
  *reinterpret_cast<uint4*>(WhvT + ((size_t)b * OUTF_ + c) * N_ + n0) = pk;

  // ---- fused dots: wave wv covers channels (wv&1)*64..+63 of rows rg*8..rg*8+7
  const int lane = t & 63;
  const int wv   = t >> 6;
  const bool pos = (wv & 1) == 0;      // even wave: ch 0..63 (pos half); odd: 64..127 (neg)
  const float al = pos ? alp[lane] : aln[lane];
  const float ar = pos ? arp[lane] : arn[lane];
  float sl[8], sr2[8];
  #pragma unroll
  for (int r = 0; r < 8; ++r) { sl[r] = acc[r] * al; sr2[r] = acc[r] * ar; }
  #pragma unroll
  for (int off = 32; off; off >>= 1) {
    #pragma unroll
    for (int r = 0; r < 8; ++r) {
      sl[r]  += __shfl_xor(sl[r],  off);
      sr2[r] += __shfl_xor(sr2[r], off);
    }
  }
  if (lane == 0) {
    #pragma unroll
    for (int r = 0; r < 8; ++r) {
      const int node = (int)row0 + rg * 8 + r;
      if (pos) { lposv[node] = sl[r] * LOG2E_; rposv[node] = sr2[r] * LOG2E_; }
      else     { lnegv[node] = sl[r] * LOG2E_; rnegv[node] = sr2[r] * LOG2E_; }
    }
  }
}

// ---------------- Kernel D1: attention rows, 4 j's/thread; light sum tail; no abf ----------------
// 8192 blocks x 512 threads = one row per block; thread t covers j = t*4..t*4+3.
// Math identical to r10/r11's passing versions; abf write removed (-33.5 MB HBM).
__global__ __launch_bounds__(512) void attn_v3d(
    const int* __restrict__ adj,
    const float* __restrict__ lposv, const float* __restrict__ rposv,
    const float* __restrict__ lnegv, const float* __restrict__ rnegv,
    const float* __restrict__ scal, float* __restrict__ out1) {
  __shared__ float sums[16];   // [P:0..7 | N:8..15] per wave
  const int t = threadIdx.x;
  const int lane = t & 63;
  const int wv = t >> 6;
  const int flat = blockIdx.x;        // b*N + i
  const int b = flat >> 11;

  const float lam = scal[12];
  float srcP = -1.0e30f, srcN = -1.0e30f;
  if (lane >= 1 && lane <= 5) { srcP = scal[lane]; srcN = scal[6 + lane]; }
  const int iSrcP = __float_as_int(srcP);
  const int iSrcN = __float_as_int(srcN);

  const float lP = lposv[flat];
  const float lN = lnegv[flat];
  const int j0 = t * 4;
  int4   av4 = *reinterpret_cast<const int4*>(adj + (size_t)flat * N_ + j0);
  float4 rp4 = *reinterpret_cast<const float4*>(rposv + b * N_ + j0);
  float4 rn4 = *reinterpret_cast<const float4*>(rnegv + b * N_ + j0);
  int   av[4] = {av4.x, av4.y, av4.z, av4.w};
  float rp[4] = {rp4.x, rp4.y, rp4.z, rp4.w};
  float rn[4] = {rn4.x, rn4.y, rn4.z, rn4.w};

  float p[4], n[4];
  #pragma unroll
  for (int q = 0; q < 4; ++q) {
    float rsp = __int_as_float(__builtin_amdgcn_ds_bpermute(av[q] << 2, iSrcP));
    float rsn = __int_as_float(__builtin_amdgcn_ds_bpermute(av[q] << 2, iSrcN));
    float e  = lP + rp[q] + rsp;
    float en = lN + rn[q] + rsn;
    e  = fmaxf(e, 0.2f * e);                 // leaky (pos scale commutes with log2e)
    en = fmaxf(en, 0.2f * en);
    p[q] = __builtin_amdgcn_exp2f(e);
    n[q] = __builtin_amdgcn_exp2f(en);
  }
  float sP = (p[0] + p[1]) + (p[2] + p[3]);
  float sN = (n[0] + n[1]) + (n[2] + n[3]);
  #pragma unroll
  for (int off = 32; off; off >>= 1) { sP += __shfl_xor(sP, off); sN += __shfl_xor(sN, off); }
  if (lane == 0) { sums[wv] = sP; sums[8 + wv] = sN; }
  __syncthreads();
  float vP = sums[lane & 7];
  vP += __shfl_xor(vP, 1); vP += __shfl_xor(vP, 2); vP += __shfl_xor(vP, 4);
  float vN = sums[8 + (lane & 7)];
  vN += __shfl_xor(vN, 1); vN += __shfl_xor(vN, 2); vN += __shfl_xor(vN, 4);
  const float s1 = 1.f / vP;
  const float s2 = -lam / vN;

  float a[4];
  #pragma unroll
  for (int q = 0; q < 4; ++q) a[q] = p[q] * s1 + n[q] * s2;
  float* o1 = out1 + (size_t)flat * N_ + j0;
  *reinterpret_cast<float4*>(o1) = make_float4(a[0], a[1], a[2], a[3]);
}

// ---------------- Kernel D2: PV via MFMA (r10-passing pv_v5, fp32 staging only) ----------------
// 512 blocks x 512 threads (8 waves, one 16-ch tile each, 2 acc chains).
// A staged fp32 -> bf16 (pack2, same RNE values the abf panel held) into XOR-swizzled LDS.
__global__ __launch_bounds__(512) void pv_v5b(
    const float* __restrict__ attn, const unsigned short* __restrict__ WhvT,
    const float* __restrict__ gamma, const float* __restrict__ beta,
    float* __restrict__ out0) {
  __shared__ __align__(16) uint4 A4[2][16 * 32];   // [buf][row*32 + unit(16B)], 16KB
  __shared__ __align__(16) float hp[16][132];
  const int t = threadIdx.x;
  const int lane = t & 63;
  const int w = t >> 6;
  const int bi = blockIdx.x;
  const int b  = bi >> 7;
  const int i0 = (bi & 127) * 16;

  // ---- staging coords: thread covers row sr, one 16B unit sj (8 bf16 = 8 k's)
  const int sr = t >> 5;
  const int sj = t & 31;
  const float4* src4 = reinterpret_cast<const float4*>(
      attn + ((size_t)(b * N_ + i0 + sr)) * N_ + sj * 8);
  const int swz = sr & 7;
  const int ui = sr * 32 + (sj ^ swz);

  // ---- compute coords: wave w owns ch tile [w*16, w*16+16)
  const int bl  = lane & 15;   // A row / B ch within tile
  const int kg  = lane >> 4;   // k-group
  const int ch  = w * 16 + bl;
  const unsigned short* Bp = WhvT + ((size_t)b * OUTF_ + ch) * N_ + kg * 8;
  f32x4 acc0 = {0.f, 0.f, 0.f, 0.f};   // even chunks
  f32x4 acc1 = {0.f, 0.f, 0.f, 0.f};   // odd chunks
  const int arow = bl * 32;
  const int aswz = bl & 7;

  // stage chunk 0
  {
    float4 s0 = src4[0], s1 = src4[1];
    uint4 u;
    u.x = pack2(s0.x, s0.y); u.y = pack2(s0.z, s0.w);
    u.z = pack2(s1.x, s1.y); u.w = pack2(s1.z, s1.w);
    A4[0][ui] = u;
  }
  __syncthreads();

  for (int c = 0; c < 8; ++c) {
    const int cur = c & 1;
    float4 s0, s1;
    if (c < 7) {  // issue next chunk's global loads before the MFMA cluster
      const int o = (c + 1) * 64;          // 64 float4 per 256-k chunk
      s0 = src4[o]; s1 = src4[o + 1];
    }
    // compute chunk c
    const unsigned short* bp = Bp + c * 256;
    #pragma unroll
    for (int kk = 0; kk < 8; ++kk) {
      bf16x8 a  = *reinterpret_cast<const bf16x8*>(&A4[cur][arow + ((kk * 4 + kg) ^ aswz)]);
      bf16x8 bv = *reinterpret_cast<const bf16x8*>(bp + kk * 32);
      if (cur == 0) acc0 = __builtin_amdgcn_mfma_f32_16x16x32_bf16(a, bv, acc0, 0, 0, 0);
      else          acc1 = __builtin_amdgcn_mfma_f32_16x16x32_bf16(a, bv, acc1, 0, 0, 0);
    }
    if (c < 7) {
      uint4 u;
      u.x = pack2(s0.x, s0.y); u.y = pack2(s0.z, s0.w);
      u.z = pack2(s1.x, s1.y); u.w = pack2(s1.z, s1.w);
      A4[cur ^ 1][ui] = u;
    }
    __syncthreads();
  }

  // ---- epilogue: acc -> hp, then LN + GELU (r4's verified 512-thread epilogue)
  #pragma unroll
  for (int q = 0; q < 4; ++q) hp[kg * 4 + q][ch] = acc0[q] + acc1[q];
  __syncthreads();

  const int row = t >> 5;
  const int c0  = t & 31;
  float v[4], s = 0.f, sq = 0.f;
  #pragma unroll
  for (int e = 0; e < 4; ++e) {
    v[e] = hp[row][c0 + e * 32];
    s += v[e]; sq += v[e] * v[e];
  }
  #pragma unroll
  for (int off = 16; off; off >>= 1) { s += __shfl_xor(s, off); sq += __shfl_xor(sq, off); }
  const float mu  = s  * (1.f / 128.f);
  const float var = sq * (1.f / 128.f) - mu * mu;
  const float inv = rsqrtf(var + EPS_);
  float* orow = out0 + ((size_t)(b * N_ + i0 + row)) * OUTF_;
  #pragma unroll
  for (int e = 0; e < 4; ++e) {
    const int chh = c0 + e * 32;
    float y = (v[e] - mu) * inv * gamma[chh] + beta[chh];
    y *= OUT_SCALE_;
    orow[chh] = 0.5f * y * (1.f + erff(y * 0.70710678118654752f));
  }
}

extern "C" void kernel_launch(void* const* d_in, const int* in_sizes, int n_in,
                              void* d_out, int out_size, void* d_ws, size_t ws_size,
                              hipStream_t stream) {
  (void)in_sizes; (void)n_in; (void)out_size; (void)ws_size;
  const float* h        = (const float*)d_in[0];
  const int*   adj      = (const int*)d_in[1];
  const float* W        = (const float*)d_in[2];
  const float* alp      = (const float*)d_in[3];
  const float* arp      = (const float*)d_in[4];
  const float* aln      = (const float*)d_in[5];
  const float* arn      = (const float*)d_in[6];
  const float* rel_emb  = (const float*)d_in[7];
  const float* a_rel_p  = (const float*)d_in[8];
  const float* a_rel_n  = (const float*)d_in[9];
  const float* ll1      = (const float*)d_in[10];
  const float* lr1      = (const float*)d_in[11];
  const float* ll2      = (const float*)d_in[12];
  const float* lr2      = (const float*)d_in[13];
  const float* gamma    = (const float*)d_in[14];
  const float* beta     = (const float*)d_in[15];

  float* out0 = (float*)d_out;                          // gelu(h'): B*N*OUTF
  float* out1 = out0 + (size_t)B_ * N_ * OUTF_;         // attention: B*N*N

  float* ws    = (float*)d_ws;
  float* scal  = ws;                    // 32 floats
  float* lposv = ws + 32;               // B*N
  float* rposv = lposv + B_ * N_;
  float* lnegv = rposv + B_ * N_;
  float* rnegv = lnegv + B_ * N_;
  float* Wh    = rnegv + B_ * N_;       // B*N*OUTF fp32
  unsigned short* WhvT = (unsigned short*)(Wh + (size_t)B_ * N_ * OUTF_);  // [B][OUTF][N] bf16

  scalars_kernel<<<1, 64, 0, stream>>>(rel_emb, a_rel_p, a_rel_n, ll1, lr1, ll2, lr2, scal);
  wh_dots_kernel<<<(B_ * N_) / 16, 256, 0, stream>>>(h, W, alp, arp, aln, arn,
                                                     Wh, WhvT, lposv, rposv, lnegv, rnegv);
  attn_v3d<<<B_ * N_, 512, 0, stream>>>(adj, lposv, rposv, lnegv, rnegv, scal, out1);
  pv_v5b<<<B_ * (N_ / 16), 512, 0, stream>>>(out1, WhvT, gamma, beta, out0);
}